// Round 13
// baseline (198.861 us; speedup 1.0000x reference)
//
#include <hip/hip_runtime.h>
#include <math.h>

// Problem constants (fixed by reference)
#define N_   32
#define CIN  32
#define COUT 16
#define D_   16
#define S_   256            // W*H
#define M_   (CIN * S_)     // 8192

#define LOG2E 1.4426950408889634f

// Partial row per (n,c,o): [0..15]=S (v-space), [16]=se, [17]=bmax, pad to 20
#define PROW 20
#define PIDX(n, c, o) ((((size_t)(n) * CIN + (c)) * COUT + (o)) * PROW)

// ws layout: [0..4KB) barrier counters (uint, memset to 0 each launch),
// then two partial buffers (floats).
#define WS_PB0 1024
#define WS_PB1 (WS_PB0 + N_ * CIN * COUT * PROW)

// LDS tile: ls[s][16 dd], 16B chunks XOR-swizzled; conflict-free b128 reads.
#define SW(s) ((((s) & 3)) ^ (((s) >> 2) & 3))

__device__ __forceinline__ void stage_load(const float* __restrict__ gsrc,
                                           int tid, float4* vals) {
  const float4* src = (const float4*)gsrc;
#pragma unroll
  for (int j = 0; j < 4; j++)
    vals[j] = src[((tid & 3) << 6) + (tid >> 2) + (j << 8)];
}

__device__ __forceinline__ void stage_store(float* ls, int tid,
                                            const float4* vals) {
#pragma unroll
  for (int j = 0; j < 4; j++) {
    int f = ((tid & 3) << 6) + (tid >> 2) + (j << 8);
    int dd = f >> 6;
    int u  = f & 63;
    int chunk = dd >> 2, lo = dd & 3;
    float vv[4] = {vals[j].x, vals[j].y, vals[j].z, vals[j].w};
#pragma unroll
    for (int m = 0; m < 4; m++) {
      int s = (u << 2) + m;
      int p = chunk ^ SW(s);
      ls[(s << 4) + (p << 2) + lo] = vv[m];
    }
  }
}

__device__ __forceinline__ void read_lp(const float* ls, int s, float* lp) {
  const float4* row = (const float4*)(ls + (s << 4));
  int sw = SW(s);
#pragma unroll
  for (int c = 0; c < 4; c++) {
    float4 q = row[c ^ sw];
    lp[c * 4 + 0] = q.x; lp[c * 4 + 1] = q.y;
    lp[c * 4 + 2] = q.z; lp[c * 4 + 3] = q.w;
  }
}

__device__ __forceinline__ float dot16(const float* a, const float* b) {
  float a0 = 0.f, a1 = 0.f, a2 = 0.f, a3 = 0.f;
#pragma unroll
  for (int k = 0; k < 4; k++) {
    a0 = fmaf(a[k],      b[k],      a0);
    a1 = fmaf(a[4 + k],  b[4 + k],  a1);
    a2 = fmaf(a[8 + k],  b[8 + k],  a2);
    a3 = fmaf(a[12 + k], b[12 + k], a3);
  }
  return (a0 + a1) + (a2 + a3);
}

__device__ __forceinline__ void make_WG(const float* __restrict__ wgt,
                                        int c, int o, const float* Greg,
                                        float* WG) {
  float wreg[16];
  const float4* wp = (const float4*)(wgt + (c * COUT + o) * 16);
#pragma unroll
  for (int i = 0; i < 4; i++) {
    float4 t = wp[i];
    wreg[i * 4 + 0] = t.x; wreg[i * 4 + 1] = t.y;
    wreg[i * 4 + 2] = t.z; wreg[i * 4 + 3] = t.w;
  }
#pragma unroll
  for (int i = 0; i < 4; i++)
#pragma unroll
    for (int j = 0; j < 4; j++) {
      float acc = 0.f;
#pragma unroll
      for (int k = 0; k < 4; k++)
        acc = fmaf(wreg[j * 4 + k], Greg[i * 4 + k], acc);
      WG[i * 4 + j] = acc * LOG2E;
    }
}

// unroll-4 only: full unroll hoists all ds_reads and spills (R9: 60 MB/pass).
__device__ __forceinline__ void sweep(const float* ls, const float* WG,
                                      float shift, int strip, int doDump,
                                      float* __restrict__ edp,
                                      float& se, float& bmx, float* E) {
  se = 0.f; bmx = -INFINITY;
#pragma unroll
  for (int d = 0; d < 16; d++) E[d] = 0.f;
#pragma unroll 4
  for (int it = 0; it < 16; it++) {
    float lp[16];
    read_lp(ls, strip + (it << 4), lp);
    float b = dot16(lp, WG) - shift;
    float e = exp2f(b);
    if (doDump) edp[(size_t)(it << 4) * COUT] = e;
    bmx = fmaxf(bmx, b);
    se += e;
#pragma unroll
    for (int d = 0; d < 16; d++) E[d] = fmaf(e, lp[d], E[d]);
  }
#pragma unroll
  for (int off = 16; off <= 32; off <<= 1) {
    se += __shfl_xor(se, off);
    bmx = fmaxf(bmx, __shfl_xor(bmx, off));
#pragma unroll
    for (int d = 0; d < 16; d++) E[d] += __shfl_xor(E[d], off);
  }
}

__device__ __forceinline__ void tail_store(const float* __restrict__ wgt,
                                           int c, int o, float (*red2)[16],
                                           float* __restrict__ part_out,
                                           int n, float shift) {
  float wt[16];
  const float4* wp = (const float4*)(wgt + (c * COUT + o) * 16);
#pragma unroll
  for (int i = 0; i < 4; i++) {
    float4 t = wp[i];
    wt[i * 4 + 0] = t.x; wt[i * 4 + 1] = t.y;
    wt[i * 4 + 2] = t.z; wt[i * 4 + 3] = t.w;
  }
  float Et[16];
#pragma unroll
  for (int d = 0; d < 16; d++) Et[d] = red2[d][o];
  float* p0 = part_out + PIDX(n, c, o);
  float4* p4 = (float4*)p0;
#pragma unroll
  for (int i = 0; i < 4; i++) {
    float s0 = 0.f, s1 = 0.f, s2 = 0.f, s3 = 0.f;
#pragma unroll
    for (int j = 0; j < 4; j++) {
      s0 = fmaf(Et[i * 4 + j], wt[j * 4 + 0], s0);
      s1 = fmaf(Et[i * 4 + j], wt[j * 4 + 1], s1);
      s2 = fmaf(Et[i * 4 + j], wt[j * 4 + 2], s2);
      s3 = fmaf(Et[i * 4 + j], wt[j * 4 + 3], s3);
    }
    p4[i] = make_float4(s0, s1, s2, s3);
  }
  p0[16] = red2[16][o];
  p0[17] = red2[17][o] + shift;  // absolute-scale bmax for next pass's shift
}

// Full per-tile pipeline: sweep + cross-wave merge + partial store.
__device__ __forceinline__ void pass_tile(const float* ls,
                                          const float* __restrict__ wgt,
                                          int c, int n, const float* Greg,
                                          float shift, float* edump,
                                          float* part_out,
                                          float (*red)[18][16],
                                          float (*red2)[16], int tid) {
  const int o = tid & 15, strip = tid >> 4, w = tid >> 6;
  float WG[16];
  make_WG(wgt, c, o, Greg, WG);
  float se, bmx, E[16];
  float* edp = edump
      ? edump + ((size_t)(n * M_ + c * S_ + strip)) * COUT + o : nullptr;
  sweep(ls, WG, shift, strip, edump != nullptr, edp, se, bmx, E);
  if ((tid & 63) < 16) {
#pragma unroll
    for (int d = 0; d < 16; d++) red[w][d][o] = E[d];
    red[w][16][o] = se;
    red[w][17][o] = bmx;
  }
  __syncthreads();
  for (int p = tid; p < 288; p += 256) {
    int f = p >> 4, oo = p & 15;
    float v0 = red[0][f][oo], v1 = red[1][f][oo];
    float v2 = red[2][f][oo], v3 = red[3][f][oo];
    red2[f][oo] = (f == 17) ? fmaxf(fmaxf(v0, v1), fmaxf(v2, v3))
                            : ((v0 + v1) + (v2 + v3));
  }
  __syncthreads();
  if (tid < 16) tail_store(wgt, c, tid, red2, part_out, n, shift);
}

// head (wave 0): merge 32 per-c rows for n. hd[o][0..15] = dG = coef*Sg,
// [16] = bmax (next shift), [17] = 1/se.
__device__ __forceinline__ void head_hd(const float* __restrict__ part,
                                        int n, int tid, float (*hd)[20]) {
  if (tid < 64) {
    const int ho = tid & 15, hs = tid >> 4;
    float H[18];
#pragma unroll
    for (int f = 0; f < 17; f++) H[f] = 0.f;
    H[17] = -INFINITY;
#pragma unroll 2
    for (int q = 0; q < 8; q++) {
      const float* r = part + PIDX(n, hs + 4 * q, ho);
      const float4* r4 = (const float4*)r;
#pragma unroll
      for (int i = 0; i < 4; i++) {
        float4 v = r4[i];
        H[i * 4 + 0] += v.x; H[i * 4 + 1] += v.y;
        H[i * 4 + 2] += v.z; H[i * 4 + 3] += v.w;
      }
      H[16] += r[16];
      H[17] = fmaxf(H[17], r[17]);
    }
#pragma unroll
    for (int off = 16; off <= 32; off <<= 1) {
#pragma unroll
      for (int f = 0; f < 17; f++) H[f] += __shfl_xor(H[f], off);
      H[17] = fmaxf(H[17], __shfl_xor(H[17], off));
    }
    if (tid < 16) {
      float inv = 1.0f / H[16], n2 = 0.f, Sg[16];
#pragma unroll
      for (int d = 0; d < 16; d++) { Sg[d] = H[d] * inv; n2 = fmaf(Sg[d], Sg[d], n2); }
      float coef = n2 / ((1.f + n2) * (sqrtf(n2) + 1e-6f));
      float4* hq = (float4*)hd[tid];
#pragma unroll
      for (int i = 0; i < 4; i++)
        hq[i] = make_float4(coef * Sg[i * 4 + 0], coef * Sg[i * 4 + 1],
                            coef * Sg[i * 4 + 2], coef * Sg[i * 4 + 3]);
      hd[tid][16] = H[17];
      hd[tid][17] = inv;
    }
  }
}

__device__ __forceinline__ unsigned agent_load(unsigned* p) {
#if __has_builtin(__hip_atomic_load)
  return __hip_atomic_load(p, __ATOMIC_RELAXED, __HIP_MEMORY_SCOPE_AGENT);
#else
  return atomicAdd(p, 0u);
#endif
}

// Two-level device-wide barrier. bar[n*16]: per-n arrival counters (16
// blocks/n); bar[512]: n-group counter (+32/phase). Monotonic targets.
// SAFE: grid 512 at 2 blocks/CU capacity (LDS 39.3KB->4, VGPR<=256->2,
// waves 8<=32) => all blocks resident at dispatch, no deadlock.
__device__ __forceinline__ void grid_barrier(unsigned* bar, int n, int phase,
                                             int tid) {
  __syncthreads();  // all threads' global stores drained (vmcnt 0)
  if (tid == 0) {
    __threadfence();  // release: wb L2 to device coherence point
    unsigned prev = atomicAdd(&bar[n * 16], 1u);
    if (prev + 1 == (unsigned)(phase * 16)) atomicAdd(&bar[512], 1u);
    while (agent_load(&bar[512]) < (unsigned)(phase * 32))
      __builtin_amdgcn_s_sleep(32);
    __threadfence();  // acquire: invalidate L1/L2
  }
  __syncthreads();
}

// Single persistent kernel: 3 routing passes + a/g epilogue, 2 grid
// barriers between passes + 1 before epilogue. Tiles LDS-resident throughout.
__global__ __launch_bounds__(256, 2) void fused_kernel(
    const float* __restrict__ l, const float* __restrict__ wgt,
    const float* __restrict__ g0, float* __restrict__ ws_f,
    unsigned* __restrict__ bar, float* __restrict__ a_out,
    float* __restrict__ g_out) {
  const int bid = blockIdx.x;
  const int n  = bid >> 4;
  const int c0 = bid & 15;
  const int c1 = c0 + 16;
  const int tid = threadIdx.x;
  const int o = tid & 15;

  __shared__ float lsA[D_ * S_];     // 16 KB, resident all 3 passes
  __shared__ float lsB[D_ * S_];     // 16 KB
  __shared__ float red[4][18][16];
  __shared__ float red2[18][16];
  __shared__ float hd[16][20];

  float* PB0 = ws_f + WS_PB0;
  float* PB1 = ws_f + WS_PB1;

  {
    float4 va[4];
    stage_load(l + ((size_t)(n * CIN + c0)) * D_ * S_, tid, va);
    stage_store(lsA, tid, va);
  }
  {
    float4 vb[4];
    stage_load(l + ((size_t)(n * CIN + c1)) * D_ * S_, tid, vb);
    stage_store(lsB, tid, vb);
  }

  float Greg[16];  // carried in registers across all passes
  {
    const float4* gp = (const float4*)(g0 + (n * COUT + o) * 16);
#pragma unroll
    for (int i = 0; i < 4; i++) {
      float4 u = gp[i];
      Greg[i * 4 + 0] = u.x; Greg[i * 4 + 1] = u.y;
      Greg[i * 4 + 2] = u.z; Greg[i * 4 + 3] = u.w;
    }
  }

  __syncthreads();  // tiles staged

  float shift = 0.f;

  // ---- pass 0 ----
  pass_tile(lsA, wgt, c0, n, Greg, shift, nullptr, PB0, red, red2, tid);
  pass_tile(lsB, wgt, c1, n, Greg, shift, nullptr, PB0, red, red2, tid);
  grid_barrier(bar, n, 1, tid);

  // ---- pass 1 ----
  head_hd(PB0, n, tid, hd);
  __syncthreads();
  {
    const float4* hq = (const float4*)hd[o];
#pragma unroll
    for (int i = 0; i < 4; i++) {
      float4 v = hq[i];
      Greg[i * 4 + 0] += v.x; Greg[i * 4 + 1] += v.y;
      Greg[i * 4 + 2] += v.z; Greg[i * 4 + 3] += v.w;
    }
    shift = hd[o][16];
  }
  pass_tile(lsA, wgt, c0, n, Greg, shift, nullptr, PB1, red, red2, tid);
  pass_tile(lsB, wgt, c1, n, Greg, shift, nullptr, PB1, red, red2, tid);
  grid_barrier(bar, n, 2, tid);

  // ---- pass 2 (dump e = exp2(b - shift) to a_out) ----
  head_hd(PB1, n, tid, hd);
  __syncthreads();
  {
    const float4* hq = (const float4*)hd[o];
#pragma unroll
    for (int i = 0; i < 4; i++) {
      float4 v = hq[i];
      Greg[i * 4 + 0] += v.x; Greg[i * 4 + 1] += v.y;
      Greg[i * 4 + 2] += v.z; Greg[i * 4 + 3] += v.w;
    }
    shift = hd[o][16];
  }
  pass_tile(lsA, wgt, c0, n, Greg, shift, a_out, PB0, red, red2, tid);
  pass_tile(lsB, wgt, c1, n, Greg, shift, a_out, PB0, red, red2, tid);
  grid_barrier(bar, n, 3, tid);

  // ---- epilogue: sinv per (n,o); rescale own e slices; g_out by c0==0 ----
  head_hd(PB0, n, tid, hd);
  __syncthreads();

  if (c0 == 0 && tid < 16) {  // g_out row = dG of final head = squash(S/se)
    const float4* hq = (const float4*)hd[tid];
    float4* g4 = (float4*)(g_out + (n * COUT + tid) * 16);
#pragma unroll
    for (int i = 0; i < 4; i++) g4[i] = hq[i];
  }

  const int q = tid & 3;  // float4 slot -> o block q*4..q*4+3
  float s0 = hd[(q << 2) + 0][17], s1 = hd[(q << 2) + 1][17];
  float s2 = hd[(q << 2) + 2][17], s3 = hd[(q << 2) + 3][17];
#pragma unroll
  for (int t = 0; t < 2; t++) {
    const int c = t ? c1 : c0;
    float4* pv = (float4*)(a_out + ((size_t)(n * M_ + c * S_)) * COUT);
#pragma unroll
    for (int r = 0; r < 4; r++) {
      int i4 = tid + (r << 8);
      float4 v = pv[i4];
      v.x *= s0; v.y *= s1; v.z *= s2; v.w *= s3;
      pv[i4] = v;
    }
  }
}

extern "C" void kernel_launch(void* const* d_in, const int* in_sizes, int n_in,
                              void* d_out, int out_size, void* d_ws, size_t ws_size,
                              hipStream_t stream) {
  const float* l = (const float*)d_in[0];
  const float* g = (const float*)d_in[1];
  const float* w = (const float*)d_in[2];
  // d_in[3] = num_iters (always 3 per setup_inputs)

  float* out = (float*)d_out;
  float* ws = (float*)d_ws;
  float* a_out = out;
  float* g_out = out + (size_t)N_ * M_ * COUT;

  // zero the barrier counters (first 4 KB of ws) — captured fine (R7)
  hipMemsetAsync(d_ws, 0, 4096, stream);

  fused_kernel<<<N_ * 16, 256, 0, stream>>>(l, w, g, ws, (unsigned*)d_ws,
                                            a_out, g_out);
}